// Round 5
// baseline (80.785 us; speedup 1.0000x reference)
//
#include <hip/hip_runtime.h>

#define M 24          // LPC order
#define NE (M + 1)    // elements per row = 25
#define NT 256        // threads per block

__global__ __launch_bounds__(NT) void levinson_kernel(const float* __restrict__ r,
                                                      float* __restrict__ out) {
    // 16B-aligned so float4 (ds_*_b128) access is always legal
    __shared__ __align__(16) float lds[NT * NE];      // 25600 B
    const int t = threadIdx.x;
    const long long blockBase = (long long)blockIdx.x * (NT * NE); // in floats

    // ---- coalesced global -> LDS (float4), 6400 floats = 1600 float4 per block ----
    {
        const float4* __restrict__ rin = (const float4*)(r + blockBase);
        float4* ldst = (float4*)lds;
#pragma unroll
        for (int k = 0; k < 7; ++k) {
            int idx = k * NT + t;
            if (idx < (NT * NE) / 4) ldst[idx] = rin[idx];
        }
    }
    __syncthreads();

    // ---- per-thread row from LDS (stride 25 = odd -> conflict-free) ----
    float rr[NE];
#pragma unroll
    for (int e = 0; e < NE; ++e) rr[e] = lds[t * NE + e];

    // ---- Levinson-Durbin: solve R a = -r1, E = r0 * prod(1-k^2) ----
    float a[M];
    float E = rr[0];
    {
        float k1 = -rr[1] / E;
        a[0] = k1;
        E *= (1.0f - k1 * k1);
    }
#pragma unroll
    for (int i = 2; i <= M; ++i) {
        // acc = r_i + sum_{j=1}^{i-1} a_j * r_{i-j}
        float acc = rr[i];
#pragma unroll
        for (int j = 1; j < i; ++j) acc = fmaf(a[j - 1], rr[i - j], acc);
        float k = -acc / E;
        // symmetric in-place update: a_new[j] = a[j] + k * a[i-2-j], j=0..i-2
#pragma unroll
        for (int lo = 0; lo < (i - 1) / 2; ++lo) {
            int hi = i - 2 - lo;
            float alo = a[lo], ahi = a[hi];
            a[lo] = fmaf(k, ahi, alo);
            a[hi] = fmaf(k, alo, ahi);
        }
        if ((i - 1) & 1) {                 // middle element when i-1 is odd
            int mid = (i - 2) / 2;
            a[mid] = fmaf(k, a[mid], a[mid]);
        }
        a[i - 1] = k;
        E *= (1.0f - k * k);
    }
    float K = sqrtf(E);

    // ---- stage output row to LDS (stride 25 write, conflict-free) ----
    __syncthreads();                       // all rr reads done before overwrite
    lds[t * NE + 0] = K;
#pragma unroll
    for (int j = 0; j < M; ++j) lds[t * NE + 1 + j] = a[j];
    __syncthreads();

    // ---- coalesced LDS -> global (float4) ----
    {
        float4* __restrict__ wout = (float4*)(out + blockBase);
        const float4* ldsrc = (const float4*)lds;
#pragma unroll
        for (int k = 0; k < 7; ++k) {
            int idx = k * NT + t;
            if (idx < (NT * NE) / 4) wout[idx] = ldsrc[idx];
        }
    }
}

extern "C" void kernel_launch(void* const* d_in, const int* in_sizes, int n_in,
                              void* d_out, int out_size, void* d_ws, size_t ws_size,
                              hipStream_t stream) {
    const float* r = (const float*)d_in[0];
    float* out = (float*)d_out;
    const int batch = in_sizes[0] / NE;          // 262144
    const int blocks = batch / NT;               // 1024
    levinson_kernel<<<blocks, NT, 0, stream>>>(r, out);
}

// Round 6
// 79.841 us; speedup vs baseline: 1.0118x; 1.0118x over previous
//
#include <hip/hip_runtime.h>

#define M 24          // LPC order
#define NE (M + 1)    // elements per row = 25
#define NT 256        // threads per block

// rcp + one Newton step: rel err ~1e-7, vs full-precision divide's long
// v_div_scale/v_div_fmas/v_div_fixup chain on the serial critical path.
__device__ __forceinline__ float fast_rcp(float x) {
    float r = __builtin_amdgcn_rcpf(x);
    return r * (2.0f - x * r);
}

__global__ __launch_bounds__(NT) void levinson_kernel(const float* __restrict__ r,
                                                      float* __restrict__ out) {
    __shared__ __align__(16) float lds[NT * NE];      // 25600 B
    const int t = threadIdx.x;
    const long long blockBase = (long long)blockIdx.x * (NT * NE); // in floats

    // ---- coalesced global -> LDS (float4), 1600 float4 per block ----
    {
        const float4* __restrict__ rin = (const float4*)(r + blockBase);
        float4* ldst = (float4*)lds;
#pragma unroll
        for (int k = 0; k < 7; ++k) {
            int idx = k * NT + t;
            if (idx < (NT * NE) / 4) ldst[idx] = rin[idx];
        }
    }
    __syncthreads();

    // ---- per-thread row from LDS (stride 25 = odd -> conflict-free) ----
    float rr[NE];
#pragma unroll
    for (int e = 0; e < NE; ++e) rr[e] = lds[t * NE + e];

    // ---- Levinson-Durbin: solve R a = -r1, E = r0 * prod(1-k^2) ----
    float a[M];
    float E = rr[0];
    {
        float k1 = -rr[1] * fast_rcp(E);
        a[0] = k1;
        E *= (1.0f - k1 * k1);
    }
#pragma unroll
    for (int i = 2; i <= M; ++i) {
        // acc = r_i + sum_{j=1}^{i-1} a_j * r_{i-j}, 2-way split to halve
        // the dependent-FMA chain (manual reassociation; fp-safe for our tol)
        float acc0 = rr[i], acc1 = 0.0f;
#pragma unroll
        for (int j = 1; j < i; j += 2) acc0 = fmaf(a[j - 1], rr[i - j], acc0);
#pragma unroll
        for (int j = 2; j < i; j += 2) acc1 = fmaf(a[j - 1], rr[i - j], acc1);
        float acc = acc0 + acc1;

        float k = -acc * fast_rcp(E);
        // symmetric in-place update: a_new[j] = a[j] + k * a[i-2-j]
#pragma unroll
        for (int lo = 0; lo < (i - 1) / 2; ++lo) {
            int hi = i - 2 - lo;
            float alo = a[lo], ahi = a[hi];
            a[lo] = fmaf(k, ahi, alo);
            a[hi] = fmaf(k, alo, ahi);
        }
        if ((i - 1) & 1) {                 // middle element when i-1 is odd
            int mid = (i - 2) / 2;
            a[mid] = fmaf(k, a[mid], a[mid]);
        }
        a[i - 1] = k;
        E *= (1.0f - k * k);
    }
    float K = sqrtf(E);

    // ---- stage output row to LDS (stride 25 write, conflict-free) ----
    __syncthreads();                       // all rr reads done before overwrite
    lds[t * NE + 0] = K;
#pragma unroll
    for (int j = 0; j < M; ++j) lds[t * NE + 1 + j] = a[j];
    __syncthreads();

    // ---- coalesced LDS -> global (float4) ----
    {
        float4* __restrict__ wout = (float4*)(out + blockBase);
        const float4* ldsrc = (const float4*)lds;
#pragma unroll
        for (int k = 0; k < 7; ++k) {
            int idx = k * NT + t;
            if (idx < (NT * NE) / 4) wout[idx] = ldsrc[idx];
        }
    }
}

extern "C" void kernel_launch(void* const* d_in, const int* in_sizes, int n_in,
                              void* d_out, int out_size, void* d_ws, size_t ws_size,
                              hipStream_t stream) {
    const float* r = (const float*)d_in[0];
    float* out = (float*)d_out;
    const int batch = in_sizes[0] / NE;          // 262144
    const int blocks = batch / NT;               // 1024
    levinson_kernel<<<blocks, NT, 0, stream>>>(r, out);
}